// Round 15
// baseline (143.308 us; speedup 1.0000x reference)
//
#include <hip/hip_runtime.h>
#include <cstddef>

typedef __attribute__((ext_vector_type(8))) short short8;
typedef __attribute__((ext_vector_type(4))) float f4;
typedef __attribute__((ext_vector_type(4))) unsigned int u4;
typedef __attribute__((ext_vector_type(2))) unsigned int u2;

__device__ __forceinline__ unsigned int f2bf(float f){
  unsigned int u = __float_as_uint(f);
  u += 0x7fffu + ((u >> 16) & 1u);   // RNE to bf16
  return u >> 16;
}
__device__ __forceinline__ float bflo(unsigned int w){ return __uint_as_float((w & 0xFFFFu) << 16); }
__device__ __forceinline__ float bfhi(unsigned int w){ return __uint_as_float(w & 0xFFFF0000u); }
__device__ __forceinline__ float fsign(float x){ return (x > 0.f) ? 1.f : ((x < 0.f) ? -1.f : 0.f); }
__device__ __forceinline__ float hclip(float x){ return fminf(1.f, fmaxf(-1.f, x)); }

#define SB0 __builtin_amdgcn_sched_barrier(0)

// lgkm-only barrier (vmem loads stay in flight)
#define BARRIER() do { \
    SB0; \
    asm volatile("s_waitcnt lgkmcnt(0)" ::: "memory"); \
    __builtin_amdgcn_s_barrier(); \
    asm volatile("" ::: "memory"); \
    SB0; \
  } while(0)

// ---------------- prep: sign weights -> bf16 {+1,-1,0} ----------------------------------------
// W1 -> FRAGMENT-MAJOR layout W'[k>>5][n][ (k>>3)&3 ][k&7]: a wave's B-fragment load becomes
// 64 lanes x 16B = 1KB CONTIGUOUS (direct global->register MFMA operands, no LDS).
// W2 -> old row-major (gemm2 unchanged).
__global__ void prep_sign_k(const float* __restrict__ W1, unsigned short* __restrict__ w1f,
                            const float* __restrict__ W2, unsigned short* __restrict__ w2s){
  int i = (blockIdx.x * blockDim.x + threadIdx.x) * 8;
  if (i < 1048576){
    int n = i >> 12, k = i & 4095;
    f4 a = *(const f4*)(W1 + i);
    f4 b = *(const f4*)(W1 + i + 4);
    u4 v;
    v.x = (unsigned)((a[0] > 0.f) ? 0x3F80u : (a[0] < 0.f ? 0xBF80u : 0u))
        | ((unsigned)((a[1] > 0.f) ? 0x3F80u : (a[1] < 0.f ? 0xBF80u : 0u)) << 16);
    v.y = (unsigned)((a[2] > 0.f) ? 0x3F80u : (a[2] < 0.f ? 0xBF80u : 0u))
        | ((unsigned)((a[3] > 0.f) ? 0x3F80u : (a[3] < 0.f ? 0xBF80u : 0u)) << 16);
    v.z = (unsigned)((b[0] > 0.f) ? 0x3F80u : (b[0] < 0.f ? 0xBF80u : 0u))
        | ((unsigned)((b[1] > 0.f) ? 0x3F80u : (b[1] < 0.f ? 0xBF80u : 0u)) << 16);
    v.w = (unsigned)((b[2] > 0.f) ? 0x3F80u : (b[2] < 0.f ? 0xBF80u : 0u))
        | ((unsigned)((b[3] > 0.f) ? 0x3F80u : (b[3] < 0.f ? 0xBF80u : 0u)) << 16);
    size_t ob = ((size_t)(k >> 5) * 256 + (size_t)n) * 64 + (size_t)((k >> 3) & 3) * 16;
    *(u4*)((char*)w1f + ob) = v;
  } else {
    int off = i - 1048576;
    if (off >= 32768) return;
    f4 a = *(const f4*)(W2 + off);
    f4 b = *(const f4*)(W2 + off + 4);
    u4 v;
    v.x = (unsigned)((a[0] > 0.f) ? 0x3F80u : (a[0] < 0.f ? 0xBF80u : 0u))
        | ((unsigned)((a[1] > 0.f) ? 0x3F80u : (a[1] < 0.f ? 0xBF80u : 0u)) << 16);
    v.y = (unsigned)((a[2] > 0.f) ? 0x3F80u : (a[2] < 0.f ? 0xBF80u : 0u))
        | ((unsigned)((a[3] > 0.f) ? 0x3F80u : (a[3] < 0.f ? 0xBF80u : 0u)) << 16);
    v.z = (unsigned)((b[0] > 0.f) ? 0x3F80u : (b[0] < 0.f ? 0xBF80u : 0u))
        | ((unsigned)((b[1] > 0.f) ? 0x3F80u : (b[1] < 0.f ? 0xBF80u : 0u)) << 16);
    v.w = (unsigned)((b[2] > 0.f) ? 0x3F80u : (b[2] < 0.f ? 0xBF80u : 0u))
        | ((unsigned)((b[3] > 0.f) ? 0x3F80u : (b[3] < 0.f ? 0xBF80u : 0u)) << 16);
    *(u4*)(w2s + off) = v;
  }
}

// ---------------- GEMM1: h1(bf16) = x @ signW1^T + sign(b1), fused transposed col-stats ---------
// BM=32, BN=256, BK=64, 64 K-steps; 512 thr = 8 waves, wave tile 32x32; grid 512 ->
// 2 blocks/CU (LDS 8KB/block, VGPR<=128 via launch_bounds(512,4)).
// B: frag-major layout, direct global->register (1KB contiguous per load, L2-resident),
//    single register set -> ZERO B LDS, no B in barrier path. A: reg-stage depth-3 ->
//    f2bf once -> ds_write into bf16 dbuf 2x4KB. Barriers are lgkm-only; the only vmem
//    waits are compiler-counted: MFMA waits B(k) (1-step L2 slack), PACKA waits A(k+1)
//    (~1.7-step HBM slack). HBM queue never force-drains; anti-phase block covers stalls.
__global__ __launch_bounds__(512, 4) void gemm1_k(
    const float* __restrict__ x, const unsigned short* __restrict__ w1f,
    const float* __restrict__ b1, unsigned short* __restrict__ h1,
    float* __restrict__ part1s, float* __restrict__ part1q)
{
  __shared__ __align__(16) char lds[8192];   // A bf16 dbuf 2x4KB
  const int tid  = threadIdx.x;
  const int lane = tid & 63;
  const int wid  = tid >> 6;          // 0..7 -> cols wid*32..+31
  const int cl   = lane & 15;
  const int g    = lane >> 4;         // 0..3
  const int row0 = blockIdx.x * 32;

  // A staging: thread -> row tid>>4 (0..31), 4 contiguous fp32 at (tid&15)*4
  const float* xA = x + (size_t)(row0 + (tid >> 4)) * 4096 + (tid & 15) * 4;
  const int aw = (tid >> 4) * 128 + (((tid & 15) * 8) ^ (((tid >> 4) & 7) << 4));

  // B frag addresses: addr(k,ks,fn) = (k*2+ks)*32768/2... byte = (k)*32768 + ks*16384 + bof
  const char* w1p = (const char*)w1f;
  const int bof0 = (wid * 32 +  0 + cl) * 64 + g * 16;
  const int bof1 = (wid * 32 + 16 + cl) * 64 + g * 16;

  // A frag read offsets
  int afo[2][2];
  #pragma unroll
  for (int fm = 0; fm < 2; fm++){
    int m = fm * 16 + cl;
    afo[fm][0] = m * 128 + ((     g * 16) ^ ((m & 7) << 4));
    afo[fm][1] = m * 128 + ((64 + g * 16) ^ ((m & 7) << 4));
  }

  f4 acc[2][2];
  const f4 z = {0.f, 0.f, 0.f, 0.f};
  acc[0][0] = z; acc[0][1] = z; acc[1][0] = z; acc[1][1] = z;

  f4 rA0, rA1, rA2, rA3;               // 4 rotating A reg sets
  short8 B00, B01, B10, B11;           // B single set: [fn][ks]

#define ISSUEA(S, K) do { rA##S = *(const f4*)(xA + (size_t)(K) * 64); } while(0)

#define ISSUEB(K) do { \
    const char* _p = w1p + (size_t)(K) * 32768; \
    B00 = *(const short8*)(_p +         bof0); \
    B01 = *(const short8*)(_p + 16384 + bof0); \
    B10 = *(const short8*)(_p +         bof1); \
    B11 = *(const short8*)(_p + 16384 + bof1); \
  } while(0)

#define PACKA(S, AB) do { \
    u2 _v; \
    _v.x = f2bf(rA##S[0]) | (f2bf(rA##S[1]) << 16); \
    _v.y = f2bf(rA##S[2]) | (f2bf(rA##S[3]) << 16); \
    *(u2*)(lds + (AB) * 4096 + aw) = _v; \
  } while(0)

#define COMPUTE(KI) do { \
    const char* _ab = lds + ((KI) & 1) * 4096; \
    short8 _af00 = *(const short8*)(_ab + afo[0][0]); \
    short8 _af01 = *(const short8*)(_ab + afo[0][1]); \
    short8 _af10 = *(const short8*)(_ab + afo[1][0]); \
    short8 _af11 = *(const short8*)(_ab + afo[1][1]); \
    __builtin_amdgcn_s_setprio(1); \
    acc[0][0] = __builtin_amdgcn_mfma_f32_16x16x32_bf16(_af00, B00, acc[0][0], 0, 0, 0); \
    acc[0][1] = __builtin_amdgcn_mfma_f32_16x16x32_bf16(_af00, B10, acc[0][1], 0, 0, 0); \
    acc[1][0] = __builtin_amdgcn_mfma_f32_16x16x32_bf16(_af10, B00, acc[1][0], 0, 0, 0); \
    acc[1][1] = __builtin_amdgcn_mfma_f32_16x16x32_bf16(_af10, B10, acc[1][1], 0, 0, 0); \
    acc[0][0] = __builtin_amdgcn_mfma_f32_16x16x32_bf16(_af01, B01, acc[0][0], 0, 0, 0); \
    acc[0][1] = __builtin_amdgcn_mfma_f32_16x16x32_bf16(_af01, B11, acc[0][1], 0, 0, 0); \
    acc[1][0] = __builtin_amdgcn_mfma_f32_16x16x32_bf16(_af01, B01, acc[1][0], 0, 0, 0); \
    acc[1][1] = __builtin_amdgcn_mfma_f32_16x16x32_bf16(_af11, B11, acc[1][1], 0, 0, 0); \
  } while(0)
// NOTE: fixed operand bug guard — correct pairs are (af[fm][ks], B<fn><ks>); written explicitly:
#undef COMPUTE
#define COMPUTE(KI) do { \
    const char* _ab = lds + ((KI) & 1) * 4096; \
    short8 _af00 = *(const short8*)(_ab + afo[0][0]); \
    short8 _af01 = *(const short8*)(_ab + afo[0][1]); \
    short8 _af10 = *(const short8*)(_ab + afo[1][0]); \
    short8 _af11 = *(const short8*)(_ab + afo[1][1]); \
    __builtin_amdgcn_s_setprio(1); \
    acc[0][0] = __builtin_amdgcn_mfma_f32_16x16x32_bf16(_af00, B00, acc[0][0], 0, 0, 0); \
    acc[0][1] = __builtin_amdgcn_mfma_f32_16x16x32_bf16(_af00, B10, acc[0][1], 0, 0, 0); \
    acc[1][0] = __builtin_amdgcn_mfma_f32_16x16x32_bf16(_af10, B00, acc[1][0], 0, 0, 0); \
    acc[1][1] = __builtin_amdgcn_mfma_f32_16x16x32_bf16(_af10, B10, acc[1][1], 0, 0, 0); \
    acc[0][0] = __builtin_amdgcn_mfma_f32_16x16x32_bf16(_af01, B01, acc[0][0], 0, 0, 0); \
    acc[0][1] = __builtin_amdgcn_mfma_f32_16x16x32_bf16(_af01, B11, acc[0][1], 0, 0, 0); \
    acc[1][0] = __builtin_amdgcn_mfma_f32_16x16x32_bf16(_af11, B01, acc[1][0], 0, 0, 0); \
    acc[1][1] = __builtin_amdgcn_mfma_f32_16x16x32_bf16(_af11, B11, acc[1][1], 0, 0, 0); \
    __builtin_amdgcn_s_setprio(0); \
  } while(0)

// step K: compute(K) [uses B(K)], refill B(K+1) (regs reused), issue A(K+3), pack A(K+1).
// Barrier is lgkm-only: HBM A-loads keep >=1.7-step slack, B 1 step (L2).
#define STEP(K, AS3, AP1) do { \
    COMPUTE(K); \
    ISSUEB(((K) + 1 < 64) ? (K) + 1 : 63); \
    ISSUEA(AS3, ((K) + 3 < 64) ? (K) + 3 : 63); \
    SB0; \
    if ((K) < 63) PACKA(AP1, ((K) + 1) & 1); \
    BARRIER(); \
  } while(0)

  // prologue: B(0) first (oldest), A(0..2); pack A(0) (compiler waits A(0), drains B(0))
  ISSUEB(0);
  ISSUEA(0, 0); ISSUEA(1, 1); ISSUEA(2, 2);
  SB0;
  PACKA(0, 0);
  BARRIER();

  #pragma unroll 1
  for (int kk = 0; kk < 64; kk += 4){
    STEP(kk + 0, 3, 1);
    STEP(kk + 1, 0, 2);
    STEP(kk + 2, 1, 3);
    STEP(kk + 3, 2, 0);
  }
  asm volatile("s_waitcnt vmcnt(0)" ::: "memory");

#undef STEP
#undef COMPUTE
#undef PACKA
#undef ISSUEB
#undef ISSUEA

  // epilogue: bf16 h1 write + fused transposed column stats (one partial per block,col)
  #pragma unroll
  for (int fn = 0; fn < 2; fn++){
    int c = wid * 32 + fn * 16 + cl;
    float sb = fsign(b1[c]);
    float s = 0.f, q = 0.f;
    #pragma unroll
    for (int fm = 0; fm < 2; fm++){
      int rbase = row0 + fm * 16 + g * 4;
      #pragma unroll
      for (int i = 0; i < 4; i++){
        float v = acc[fm][fn][i] + sb;
        h1[(size_t)(rbase + i) * 256 + c] = (unsigned short)f2bf(v);
        s += v; q += v * v;
      }
    }
    s += __shfl_xor(s, 16, 64); s += __shfl_xor(s, 32, 64);
    q += __shfl_xor(q, 16, 64); q += __shfl_xor(q, 32, 64);
    if (g == 0){
      part1s[(size_t)c * 512 + blockIdx.x] = s;
      part1q[(size_t)c * 512 + blockIdx.x] = q;
    }
  }
}

// ---------------- BN params from transposed partials ------------------------------------------
template<int COLS, int NBLK>
__global__ __launch_bounds__(64) void params_k(
    const float* __restrict__ ps, const float* __restrict__ pq,
    const float* __restrict__ g, const float* __restrict__ be,
    float* __restrict__ ab){
  int j = blockIdx.x * 64 + threadIdx.x;
  const f4* vs = (const f4*)(ps + (size_t)j * NBLK);
  const f4* vq = (const f4*)(pq + (size_t)j * NBLK);
  f4 s4 = {0,0,0,0}, q4 = {0,0,0,0};
  #pragma unroll 8
  for (int b = 0; b < NBLK/4; b++){ s4 += vs[b]; q4 += vq[b]; }
  float s = s4[0]+s4[1]+s4[2]+s4[3];
  float q = q4[0]+q4[1]+q4[2]+q4[3];
  float mu  = s * (1.f/16384.f);
  float var = q * (1.f/16384.f) - mu*mu;
  float a   = g[j] * rsqrtf(var + 1e-5f);
  ab[j] = a;
  ab[COLS + j] = be[j] - mu*a;
}

// ---------------- GEMM2: h2(bf16) = clip(BN1(h1)) @ signW2^T + sign(b2), fused stats -----------
__global__ __launch_bounds__(512) void gemm2_k(
    const unsigned short* __restrict__ h1, const unsigned short* __restrict__ w2s,
    const float* __restrict__ b2, const float* __restrict__ ab1,
    unsigned short* __restrict__ h2, float* __restrict__ part2s, float* __restrict__ part2q)
{
  __shared__ __align__(16) char lds[32768];
  __shared__ __align__(16) float a1l[256];
  __shared__ __align__(16) float c1l[256];
  const int tid  = threadIdx.x;
  const int lane = tid & 63;
  const int wid  = tid >> 6;          // 0..7 -> cols wid*16..+15
  const int cl   = lane & 15;
  const int g    = lane >> 4;
  const int klo  = g * 8;
  const int row0 = blockIdx.x * 64;

  if (tid < 256) a1l[tid] = ab1[tid];
  else           c1l[tid - 256] = ab1[tid];

  const int am  = tid >> 3;
  const int ak0 = (tid & 7) * 8;
  const unsigned short* hA = h1 + (size_t)(row0 + am) * 256 + ak0;
  const int aw = ((am * 128) + (ak0 * 2)) ^ ((am & 7) << 4);
  const unsigned short* wbase = w2s + (size_t)(wid * 16 + cl) * 256 + klo;

  u4 q0 = *(const u4*)(hA);
  u4 q1 = *(const u4*)(hA + 64);
  u4 q2 = *(const u4*)(hA + 128);
  u4 q3 = *(const u4*)(hA + 192);
  short8 Bq0, Bq1, Br0, Br1;
  Bq0 = *(const short8*)(wbase);
  Bq1 = *(const short8*)(wbase + 32);

  BARRIER();                 // a1l/c1l visible

#define TRW(KB, RAW) do { \
    f4 _a0 = *(const f4*)(&a1l[(KB)*64 + ak0]); \
    f4 _a1 = *(const f4*)(&a1l[(KB)*64 + ak0 + 4]); \
    f4 _c0 = *(const f4*)(&c1l[(KB)*64 + ak0]); \
    f4 _c1 = *(const f4*)(&c1l[(KB)*64 + ak0 + 4]); \
    float _t0 = hclip(_a0[0]*bflo(RAW.x) + _c0[0]); \
    float _t1 = hclip(_a0[1]*bfhi(RAW.x) + _c0[1]); \
    float _t2 = hclip(_a0[2]*bflo(RAW.y) + _c0[2]); \
    float _t3 = hclip(_a0[3]*bfhi(RAW.y) + _c0[3]); \
    float _t4 = hclip(_a1[0]*bflo(RAW.z) + _c1[0]); \
    float _t5 = hclip(_a1[1]*bfhi(RAW.z) + _c1[1]); \
    float _t6 = hclip(_a1[2]*bflo(RAW.w) + _c1[2]); \
    float _t7 = hclip(_a1[3]*bfhi(RAW.w) + _c1[3]); \
    u4 _v; \
    _v.x = f2bf(_t0) | (f2bf(_t1) << 16); \
    _v.y = f2bf(_t2) | (f2bf(_t3) << 16); \
    _v.z = f2bf(_t4) | (f2bf(_t5) << 16); \
    _v.w = f2bf(_t6) | (f2bf(_t7) << 16); \
    *(u4*)(lds + (KB)*8192 + aw) = _v; \
  } while(0)

  TRW(0, q0); TRW(1, q1); TRW(2, q2); TRW(3, q3);
#undef TRW
  BARRIER();

  f4 acc[4];
  const f4 z = {0.f, 0.f, 0.f, 0.f};
  #pragma unroll
  for (int i = 0; i < 4; i++) acc[i] = z;

#define LOADB2(P, KB) do { \
    B##P##0 = *(const short8*)(wbase + (KB)*64); \
    B##P##1 = *(const short8*)(wbase + (KB)*64 + 32); \
  } while(0)

#define COMP2(BASE, P) do { \
    const char* _ab = (const char*)(BASE); \
    short8 _af[4][2]; \
    _Pragma("unroll") \
    for (int fm = 0; fm < 4; fm++){ \
      int _m = fm*16 + cl; \
      _af[fm][0] = *(const short8*)(_ab + ((_m*128 + klo*2) ^ ((_m & 7) << 4))); \
      _af[fm][1] = *(const short8*)(_ab + ((_m*128 + (32 + klo)*2) ^ ((_m & 7) << 4))); \
    } \
    _Pragma("unroll") \
    for (int fm = 0; fm < 4; fm++){ \
      acc[fm] = __builtin_amdgcn_mfma_f32_16x16x32_bf16(_af[fm][0], B##P##0, acc[fm], 0, 0, 0); \
      acc[fm] = __builtin_amdgcn_mfma_f32_16x16x32_bf16(_af[fm][1], B##P##1, acc[fm], 0, 0, 0); \
    } \
  } while(0)

  LOADB2(r, 1);
  COMP2(lds,         q);
  LOADB2(q, 2);
  COMP2(lds +  8192, r);
  LOADB2(r, 3);
  COMP2(lds + 16384, q);
  COMP2(lds + 24576, r);
#undef COMP2
#undef LOADB2

  {
    int c = wid*16 + cl;
    float sb = fsign(b2[c]);
    float s = 0.f, q = 0.f;
    #pragma unroll
    for (int fm = 0; fm < 4; fm++){
      int rbase = row0 + fm*16 + g*4;
      #pragma unroll
      for (int i = 0; i < 4; i++){
        float v = acc[fm][i] + sb;
        h2[(size_t)(rbase + i)*128 + c] = (unsigned short)f2bf(v);
        s += v; q += v*v;
      }
    }
    s += __shfl_xor(s, 16, 64); s += __shfl_xor(s, 32, 64);
    q += __shfl_xor(q, 16, 64); q += __shfl_xor(q, 32, 64);
    if (g == 0){
      part2s[c*256 + blockIdx.x] = s;
      part2q[c*256 + blockIdx.x] = q;
    }
  }
}

// ---------------- final: out = clip(BN2(h2)) @ W4^T + b4, BN2 params fused ---------------------
__global__ __launch_bounds__(128) void final_k(
    const unsigned short* __restrict__ h2,
    const float* __restrict__ part2s, const float* __restrict__ part2q,
    const float* __restrict__ g2, const float* __restrict__ be2,
    const float* __restrict__ W4, const float* __restrict__ b4,
    float* __restrict__ out)
{
  __shared__ __align__(16) float W4l[12*128];
  __shared__ __align__(16) float a2l[128];
  __shared__ __align__(16) float c2l[128];
  const int t = threadIdx.x;
  #pragma unroll
  for (int i = 0; i < 3; i++)
    *(f4*)&W4l[(i*128 + t)*4] = *(const f4*)(W4 + (i*128 + t)*4);
  {
    const f4* vs = (const f4*)(part2s + t*256);
    const f4* vq = (const f4*)(part2q + t*256);
    f4 s4 = {0,0,0,0}, q4 = {0,0,0,0};
    #pragma unroll 8
    for (int b = 0; b < 64; b++){ s4 += vs[b]; q4 += vq[b]; }
    float s = s4[0]+s4[1]+s4[2]+s4[3];
    float q = q4[0]+q4[1]+q4[2]+q4[3];
    float mu  = s * (1.f/16384.f);
    float var = q * (1.f/16384.f) - mu*mu;
    float a   = g2[t] * rsqrtf(var + 1e-5f);
    a2l[t] = a;
    c2l[t] = be2[t] - mu*a;
  }
  __syncthreads();

  const int r = blockIdx.x * 128 + t;
  const u4* hp = (const u4*)(h2 + (size_t)r * 128);
  u4 hv0 = hp[0], hv1 = hp[1], hv2 = hp[2],  hv3 = hp[3];
  u4 hv4 = hp[4], hv5 = hp[5], hv6 = hp[6],  hv7 = hp[7];
  u4 hv8 = hp[8], hv9 = hp[9], hv10 = hp[10], hv11 = hp[11];
  u4 hv12 = hp[12], hv13 = hp[13], hv14 = hp[14], hv15 = hp[15];

  float acc[12];
  #pragma unroll
  for (int o = 0; o < 12; o++) acc[o] = b4[o];

#define FPROC(HV, J) do { \
    f4 a0 = *(const f4*)&a2l[(J)*8];     f4 a1 = *(const f4*)&a2l[(J)*8 + 4]; \
    f4 c0 = *(const f4*)&c2l[(J)*8];     f4 c1 = *(const f4*)&c2l[(J)*8 + 4]; \
    float tt0 = hclip(a0[0]*bflo(HV.x) + c0[0]); \
    float tt1 = hclip(a0[1]*bfhi(HV.x) + c0[1]); \
    float tt2 = hclip(a0[2]*bflo(HV.y) + c0[2]); \
    float tt3 = hclip(a0[3]*bfhi(HV.y) + c0[3]); \
    float tt4 = hclip(a1[0]*bflo(HV.z) + c1[0]); \
    float tt5 = hclip(a1[1]*bfhi(HV.z) + c1[1]); \
    float tt6 = hclip(a1[2]*bflo(HV.w) + c1[2]); \
    float tt7 = hclip(a1[3]*bfhi(HV.w) + c1[3]); \
    _Pragma("unroll") \
    for (int o = 0; o < 12; o++){ \
      f4 w0 = *(const f4*)&W4l[o*128 + (J)*8]; \
      f4 w1 = *(const f4*)&W4l[o*128 + (J)*8 + 4]; \
      acc[o] += tt0*w0[0] + tt1*w0[1] + tt2*w0[2] + tt3*w0[3] \
              + tt4*w1[0] + tt5*w1[1] + tt6*w1[2] + tt7*w1[3]; \
    } \
  } while(0)

  FPROC(hv0, 0);  FPROC(hv1, 1);  FPROC(hv2, 2);   FPROC(hv3, 3);
  FPROC(hv4, 4);  FPROC(hv5, 5);  FPROC(hv6, 6);   FPROC(hv7, 7);
  FPROC(hv8, 8);  FPROC(hv9, 9);  FPROC(hv10, 10); FPROC(hv11, 11);
  FPROC(hv12, 12); FPROC(hv13, 13); FPROC(hv14, 14); FPROC(hv15, 15);
#undef FPROC

  #pragma unroll
  for (int o = 0; o < 12; o++) out[(size_t)r*12 + o] = acc[o];
}

// ---------------- launch ----------------
extern "C" void kernel_launch(void* const* d_in, const int* in_sizes, int n_in,
                              void* d_out, int out_size, void* d_ws, size_t ws_size,
                              hipStream_t stream)
{
  const float* x   = (const float*)d_in[0];
  const float* W1  = (const float*)d_in[1];
  const float* b1  = (const float*)d_in[2];
  const float* g1  = (const float*)d_in[3];
  const float* be1 = (const float*)d_in[4];
  const float* W2  = (const float*)d_in[5];
  const float* b2  = (const float*)d_in[6];
  const float* g2  = (const float*)d_in[7];
  const float* be2 = (const float*)d_in[8];
  const float* W4  = (const float*)d_in[9];
  const float* b4  = (const float*)d_in[10];
  float* out = (float*)d_out;

  char* ws = (char*)d_ws;
  unsigned short* h1     = (unsigned short*)(ws);              //  8 MB  [16384,256] bf16
  unsigned short* h2     = (unsigned short*)(ws + 8388608);    //  4 MB  [16384,128] bf16
  unsigned short* w1f    = (unsigned short*)(ws + 12582912);   //  2 MB  frag-major
  unsigned short* w2s    = (unsigned short*)(ws + 14680064);   // 64 KB  [128,256] bf16
  float*          part1s = (float*)(ws + 14745600);            // 512 KB [256][512]
  float*          part1q = (float*)(ws + 15269888);            // 512 KB
  float*          part2s = (float*)(ws + 15794176);            // 128 KB [128][256]
  float*          part2q = (float*)(ws + 15925248);            // 128 KB
  float*          ab1    = (float*)(ws + 16056320);            // a1[256], c1[256]

  prep_sign_k<<<528, 256, 0, stream>>>(W1, w1f, W2, w2s);
  gemm1_k<<<512, 512, 0, stream>>>(x, w1f, b1, h1, part1s, part1q);
  params_k<256, 512><<<4, 64, 0, stream>>>(part1s, part1q, g1, be1, ab1);
  gemm2_k<<<256, 512, 0, stream>>>(h1, w2s, b2, ab1, h2, part2s, part2q);
  final_k<<<128, 128, 0, stream>>>(h2, part2s, part2q, g2, be2, W4, b4, out);
}